// Round 12
// baseline (6069.307 us; speedup 1.0000x reference)
//
#include <hip/hip_runtime.h>
#include <hip/hip_bf16.h>

// L=512, B=64, D=H=512, 3H=1536.
//  gemm_k<SPLIT,TANH>: Pt/Qt = tanh(v@Wp^T)  (split-bf16 3-pass MFMA)
//  att_k: logits via tanh addition formula, softmax, c = a·v  (c bf16)
//  gemm_k<AIN,BIAS,OUTBF16>: Gi = c@W_ih^T + b_ih
//  rec_k v10 — TAG-IN-DATA sync (r11 beacon proved the "fast path" never ran;
//    all prior numbers were the flag-based MALL path). Each published h dword
//    = (bf16 << 16) | step_tag. Agent-scope (sc1) stores/loads -> MALL-visible
//    on ANY block placement; consumers poll their own data until tags match.
//    No flags, no syncthreads, no drains, no probe, no demote. Hang-impossible:
//    sc1 visibility is the r2-proven primitive; tags are monotonic.

typedef float f32x4 __attribute__((ext_vector_type(4)));
typedef short s16x8 __attribute__((ext_vector_type(8)));
typedef short s16x4 __attribute__((ext_vector_type(4)));
typedef unsigned int u32x4 __attribute__((ext_vector_type(4)));

static __device__ __forceinline__ float rcp_fast(float x) { return __builtin_amdgcn_rcpf(x); }
static __device__ __forceinline__ float tanh_fast(float x) {
    float e = __expf(2.0f * x);
    return 1.0f - 2.0f * rcp_fast(e + 1.0f);
}
static __device__ __forceinline__ float sigmoid_fast(float x) {
    return rcp_fast(1.0f + __expf(-x));
}
static __device__ __forceinline__ unsigned short f2bf(float x) {
    union { float f; unsigned u; } v; v.f = x;
    unsigned r = v.u + 0x7FFFu + ((v.u >> 16) & 1u);
    return (unsigned short)(r >> 16);
}
static __device__ __forceinline__ float bf2f(unsigned short b) {
    union { unsigned u; float f; } v; v.u = ((unsigned)b) << 16;
    return v.f;
}
static __device__ __forceinline__ s16x8 pack8(f32x4 a, f32x4 b) {
    s16x8 r;
    r[0] = (short)f2bf(a[0]); r[1] = (short)f2bf(a[1]);
    r[2] = (short)f2bf(a[2]); r[3] = (short)f2bf(a[3]);
    r[4] = (short)f2bf(b[0]); r[5] = (short)f2bf(b[1]);
    r[6] = (short)f2bf(b[2]); r[7] = (short)f2bf(b[3]);
    return r;
}
static __device__ __forceinline__ void split8(f32x4 a, f32x4 b, s16x8* hi, s16x8* lo) {
    s16x8 h, l;
#pragma unroll
    for (int e = 0; e < 4; e++) {
        unsigned short hh = f2bf(a[e]); h[e] = (short)hh;
        l[e] = (short)f2bf(a[e] - bf2f(hh));
    }
#pragma unroll
    for (int e = 0; e < 4; e++) {
        unsigned short hh = f2bf(b[e]); h[4 + e] = (short)hh;
        l[4 + e] = (short)f2bf(b[e] - bf2f(hh));
    }
    *hi = h; *lo = l;
}
static __device__ __forceinline__ f32x4 mfma16(s16x8 a, s16x8 b, f32x4 c) {
    return __builtin_amdgcn_mfma_f32_16x16x32_bf16(a, b, c, 0, 0, 0);
}
static __device__ __forceinline__ void vm_drain() {
    asm volatile("s_waitcnt vmcnt(0)" ::: "memory");
}

// ---------------------------------------------------------------------------
// GEMM (unchanged, proven)
// ---------------------------------------------------------------------------
template<int SPLIT, int TANH, int BIAS, int AIN, int OUTBF16>
__global__ __launch_bounds__(256, 2)
void gemm_k(const void* __restrict__ Ap, const float* __restrict__ Wp,
            const float* __restrict__ bias, void* __restrict__ outp,
            int M, int N)
{
    const int bm = blockIdx.x, bn = blockIdx.y;
    const int tid = threadIdx.x;
    const int w = tid >> 6, lane = tid & 63;
    const int l15 = lane & 15, l4 = lane >> 4;

    __shared__ unsigned short Al[128 * 72 * (SPLIT ? 2 : 1)];
    __shared__ unsigned short Wl[128 * 72 * (SPLIT ? 2 : 1)];
    const int LOFS = 128 * 72;

    f32x4 acc[4][4];
#pragma unroll
    for (int i = 0; i < 4; i++)
#pragma unroll
        for (int j = 0; j < 4; j++) acc[i][j] = (f32x4){0.f, 0.f, 0.f, 0.f};

    const int srow = tid >> 1, shalf = tid & 1;
    const float* Asrc = (const float*)Ap + (size_t)(bm * 128 + srow) * 512 + shalf * 32;
    const unsigned short* Asrcb = (const unsigned short*)Ap + (size_t)(bm * 128 + srow) * 512 + shalf * 32;
    const float* Wsrc = Wp + (size_t)(bn * 128 + srow) * 512 + shalf * 32;
    unsigned short* Adst = Al + srow * 72 + shalf * 32;
    unsigned short* Wdst = Wl + srow * 72 + shalf * 32;

    for (int k0 = 0; k0 < 512; k0 += 64) {
        __syncthreads();
        if (AIN) {
#pragma unroll
            for (int j = 0; j < 4; j++)
                *(s16x8*)(Adst + j * 8) = *(const s16x8*)(Asrcb + k0 + j * 8);
        } else if (SPLIT) {
#pragma unroll
            for (int j = 0; j < 4; j++) {
                f32x4 x = *(const f32x4*)(Asrc + k0 + j * 8);
                f32x4 y = *(const f32x4*)(Asrc + k0 + j * 8 + 4);
                s16x8 hi, lo; split8(x, y, &hi, &lo);
                *(s16x8*)(Adst + j * 8) = hi;
                *(s16x8*)(Adst + LOFS + j * 8) = lo;
            }
        } else {
#pragma unroll
            for (int j = 0; j < 4; j++) {
                f32x4 x = *(const f32x4*)(Asrc + k0 + j * 8);
                f32x4 y = *(const f32x4*)(Asrc + k0 + j * 8 + 4);
                *(s16x8*)(Adst + j * 8) = pack8(x, y);
            }
        }
        if (SPLIT) {
#pragma unroll
            for (int j = 0; j < 4; j++) {
                f32x4 x = *(const f32x4*)(Wsrc + k0 + j * 8);
                f32x4 y = *(const f32x4*)(Wsrc + k0 + j * 8 + 4);
                s16x8 hi, lo; split8(x, y, &hi, &lo);
                *(s16x8*)(Wdst + j * 8) = hi;
                *(s16x8*)(Wdst + LOFS + j * 8) = lo;
            }
        } else {
#pragma unroll
            for (int j = 0; j < 4; j++) {
                f32x4 x = *(const f32x4*)(Wsrc + k0 + j * 8);
                f32x4 y = *(const f32x4*)(Wsrc + k0 + j * 8 + 4);
                *(s16x8*)(Wdst + j * 8) = pack8(x, y);
            }
        }
        __syncthreads();

#pragma unroll
        for (int kt = 0; kt < 2; kt++) {
            s16x8 afh[4], bfh[4];
#pragma unroll
            for (int mb = 0; mb < 4; mb++)
                afh[mb] = *(const s16x8*)(Al + ((w & 1) * 64 + mb * 16 + l15) * 72 + kt * 32 + l4 * 8);
#pragma unroll
            for (int nb = 0; nb < 4; nb++)
                bfh[nb] = *(const s16x8*)(Wl + ((w >> 1) * 64 + nb * 16 + l15) * 72 + kt * 32 + l4 * 8);
            if (SPLIT) {
                s16x8 afl[4], bfl[4];
#pragma unroll
                for (int mb = 0; mb < 4; mb++)
                    afl[mb] = *(const s16x8*)(Al + LOFS + ((w & 1) * 64 + mb * 16 + l15) * 72 + kt * 32 + l4 * 8);
#pragma unroll
                for (int nb = 0; nb < 4; nb++)
                    bfl[nb] = *(const s16x8*)(Wl + LOFS + ((w >> 1) * 64 + nb * 16 + l15) * 72 + kt * 32 + l4 * 8);
#pragma unroll
                for (int mb = 0; mb < 4; mb++)
#pragma unroll
                    for (int nb = 0; nb < 4; nb++) {
                        acc[mb][nb] = mfma16(afh[mb], bfh[nb], acc[mb][nb]);
                        acc[mb][nb] = mfma16(afh[mb], bfl[nb], acc[mb][nb]);
                        acc[mb][nb] = mfma16(afl[mb], bfh[nb], acc[mb][nb]);
                    }
            } else {
#pragma unroll
                for (int mb = 0; mb < 4; mb++)
#pragma unroll
                    for (int nb = 0; nb < 4; nb++)
                        acc[mb][nb] = mfma16(afh[mb], bfh[nb], acc[mb][nb]);
            }
        }
    }

    const int m0 = bm * 128 + (w & 1) * 64;
    const int n0 = bn * 128 + (w >> 1) * 64;
#pragma unroll
    for (int nb = 0; nb < 4; nb++) {
        float bv = 0.0f;
        const int n = n0 + nb * 16 + l15;
        if (BIAS) bv = bias[n];
#pragma unroll
        for (int mb = 0; mb < 4; mb++) {
#pragma unroll
            for (int i = 0; i < 4; i++) {
                const int m = m0 + mb * 16 + l4 * 4 + i;
                float vv = acc[mb][nb][i];
                if (BIAS) vv += bv;
                if (TANH) vv = tanh_fast(vv);
                if (OUTBF16) ((unsigned short*)outp)[(size_t)m * N + n] = f2bf(vv);
                else        ((float*)outp)[(size_t)m * N + n] = vv;
            }
        }
    }
}

// ---------------------------------------------------------------------------
// Fused attention (unchanged, proven)
// ---------------------------------------------------------------------------
__global__ __launch_bounds__(512, 4)
void att_k(const float* __restrict__ Pt, const float* __restrict__ Qt,
           const float* __restrict__ Vv, const float* __restrict__ vin,
           unsigned short* __restrict__ cbuf)
{
    const int tblk = blockIdx.x, b = blockIdx.y;
    const int tid = threadIdx.x;
    const int w = tid >> 6, lane = tid & 63;
    const int t_in = lane >> 5, sl = lane & 31;
    const int t_loc = w * 2 + t_in;
    const int tg = tblk * 16 + t_loc;

    __shared__ float sbuf[16][513];
    __shared__ float qst[8][640];
    __shared__ float zinv[16];

    float Pa[16], Vb[16], VbA[16];
    {
        const float* pp = Pt + ((size_t)tg * 64 + b) * 512 + sl * 16;
        const float* vb = Vv + (size_t)b * 512 + sl * 16;
#pragma unroll
        for (int j = 0; j < 4; j++) {
            f32x4 x = *(const f32x4*)(pp + j * 4);
            f32x4 y = *(const f32x4*)(vb + j * 4);
#pragma unroll
            for (int e = 0; e < 4; e++) { Pa[j * 4 + e] = x[e]; Vb[j * 4 + e] = y[e]; }
        }
#pragma unroll
        for (int e = 0; e < 16; e++) VbA[e] = Vb[e] * Pa[e];
    }

    for (int l0 = 0; l0 < 512; l0 += 8) {
        __syncthreads();
        {
            const int row = tid >> 6;
            const int cb = (tid & 63) * 8;
            const float* src = Qt + ((size_t)(l0 + row) * 64 + b) * 512 + cb;
            const int f0 = cb + 4 * (cb >> 4);
            *(f32x4*)(&qst[row][f0])     = *(const f32x4*)(src);
            *(f32x4*)(&qst[row][f0 + 4]) = *(const f32x4*)(src + 4);
        }
        __syncthreads();
        for (int l = 0; l < 8; l++) {
            const float* qrow = &qst[l][sl * 20];
            float a0 = 0.f, a1 = 0.f, a2 = 0.f, a3 = 0.f;
#pragma unroll
            for (int j = 0; j < 4; j++) {
                f32x4 q = *(const f32x4*)(qrow + j * 4);
                {
                    float d = fmaf(Pa[4 * j + 0], q[0], 1.0f);
                    a0 = fmaf(fmaf(Vb[4 * j + 0], q[0], VbA[4 * j + 0]), rcp_fast(d), a0);
                }
                {
                    float d = fmaf(Pa[4 * j + 1], q[1], 1.0f);
                    a1 = fmaf(fmaf(Vb[4 * j + 1], q[1], VbA[4 * j + 1]), rcp_fast(d), a1);
                }
                {
                    float d = fmaf(Pa[4 * j + 2], q[2], 1.0f);
                    a2 = fmaf(fmaf(Vb[4 * j + 2], q[2], VbA[4 * j + 2]), rcp_fast(d), a2);
                }
                {
                    float d = fmaf(Pa[4 * j + 3], q[3], 1.0f);
                    a3 = fmaf(fmaf(Vb[4 * j + 3], q[3], VbA[4 * j + 3]), rcp_fast(d), a3);
                }
            }
            float accp = (a0 + a1) + (a2 + a3);
#pragma unroll
            for (int m = 1; m < 32; m <<= 1) accp += __shfl_xor(accp, m, 64);
            if (sl == 0) sbuf[t_loc][l0 + l] = accp;
        }
    }
    __syncthreads();

    {
        const int tr = tid >> 5;
        const int i = tid & 31;
        float m = -1e30f;
        for (int l = i; l < 512; l += 32) m = fmaxf(m, sbuf[tr][l]);
#pragma unroll
        for (int mm = 1; mm < 32; mm <<= 1) m = fmaxf(m, __shfl_xor(m, mm, 64));
        float z = 0.0f;
        for (int l = i; l < 512; l += 32) {
            float e = __expf(sbuf[tr][l] - m);
            sbuf[tr][l] = e;
            z += e;
        }
#pragma unroll
        for (int mm = 1; mm < 32; mm <<= 1) z += __shfl_xor(z, mm, 64);
        if (i == 0) zinv[tr] = rcp_fast(z);
    }
    __syncthreads();

    float ca[16];
#pragma unroll
    for (int j = 0; j < 16; j++) ca[j] = 0.0f;

    for (int l0 = 0; l0 < 512; l0 += 8) {
        __syncthreads();
        {
            const int row = tid >> 6;
            const int cb = (tid & 63) * 8;
            const float* src = vin + ((size_t)(l0 + row) * 64 + b) * 512 + cb;
            const int f0 = cb + 4 * (cb >> 4);
            *(f32x4*)(&qst[row][f0])     = *(const f32x4*)(src);
            *(f32x4*)(&qst[row][f0 + 4]) = *(const f32x4*)(src + 4);
        }
        __syncthreads();
        for (int l = 0; l < 8; l++) {
            const float a = sbuf[t_loc][l0 + l];
            const float* vrow = &qst[l][sl * 20];
#pragma unroll
            for (int j = 0; j < 4; j++) {
                f32x4 x = *(const f32x4*)(vrow + j * 4);
                ca[4 * j + 0] = fmaf(a, x[0], ca[4 * j + 0]);
                ca[4 * j + 1] = fmaf(a, x[1], ca[4 * j + 1]);
                ca[4 * j + 2] = fmaf(a, x[2], ca[4 * j + 2]);
                ca[4 * j + 3] = fmaf(a, x[3], ca[4 * j + 3]);
            }
        }
    }
    const float zi = zinv[t_loc];
    unsigned short* co = cbuf + ((size_t)tg * 64 + b) * 512 + sl * 16;
#pragma unroll
    for (int j = 0; j < 4; j++) {
        s16x4 o;
        o[0] = (short)f2bf(ca[4 * j + 0] * zi);
        o[1] = (short)f2bf(ca[4 * j + 1] * zi);
        o[2] = (short)f2bf(ca[4 * j + 2] * zi);
        o[3] = (short)f2bf(ca[4 * j + 3] * zi);
        *(s16x4*)(co + j * 4) = o;
    }
}

// ---------------------------------------------------------------------------
// rec_k v10 — tag-in-data. 64 blocks: g = bid>>3 owns b in [g*8,g*8+8),
// sub = bid&7 owns j in [sub*64,+64), wave w owns 16 j's. W_hh reg-resident.
// hbT: u32[2][64][512], entry = (bf16(h)<<16) | step_tag. Zeroed per launch.
// ---------------------------------------------------------------------------
__global__ __launch_bounds__(256, 1)
void rec_k(const unsigned short* __restrict__ Gi,
           const float* __restrict__ Whh, const float* __restrict__ bhh,
           const float* __restrict__ h0,
           unsigned int* __restrict__ hbT,
           float* __restrict__ hs)
{
    const int tid = threadIdx.x;
    const int g = blockIdx.x >> 3;
    const int sub = blockIdx.x & 7;

    const int w = tid >> 6;
    const int lane = tid & 63;
    const int l15 = lane & 15, l4 = lane >> 4;
    const int b  = g * 8 + (l15 & 7);
    const int jb = sub * 64 + w * 16;
    const int jrow = l4 * 4;
    const bool writer = (l15 < 8);

    // register-resident W A-frags
    s16x8 wf[3][16];
#pragma unroll
    for (int gg = 0; gg < 3; gg++) {
        const float* wr = Whh + (size_t)(gg * 512 + jb + l15) * 512 + l4 * 8;
#pragma unroll
        for (int c = 0; c < 16; c++) {
            f32x4 x = *(const f32x4*)(wr + c * 32);
            f32x4 y = *(const f32x4*)(wr + c * 32 + 4);
            wf[gg][c] = pack8(x, y);
        }
    }

    float bh_r[4], bh_z[4], bh_n[4];
#pragma unroll
    for (int i = 0; i < 4; i++) {
        bh_r[i] = bhh[jb + jrow + i];
        bh_z[i] = bhh[512 + jb + jrow + i];
        bh_n[i] = bhh[1024 + jb + jrow + i];
    }
    float hp[4];
#pragma unroll
    for (int i = 0; i < 4; i++) hp[i] = h0[(size_t)b * 512 + jb + jrow + i];

    s16x4 g0, g1, g2;
    {
        const unsigned short* gp = Gi + (size_t)b * 1536 + jb + jrow;
        g0 = *(const s16x4*)(gp);
        g1 = *(const s16x4*)(gp + 512);
        g2 = *(const s16x4*)(gp + 1024);
    }

// two tagged dwordx4 loads per granule c (j-range c*32+l4*8 .. +8)
#define LDT(c, o0, o1)                                                        \
    asm volatile("global_load_dwordx4 %0, %2, off offset:" o0 " sc1\n\t"       \
                 "global_load_dwordx4 %1, %2, off offset:" o1 " sc1"           \
                 : "=v"(ra[c]), "=v"(rb[c]) : "v"(src) : "memory");

    for (int t = 0; t < 512; t++) {
        s16x8 hfrag[16];
        if (t == 0) {
            const float* hr = h0 + (size_t)b * 512 + l4 * 8;
#pragma unroll
            for (int c = 0; c < 16; c++) {
                f32x4 x = *(const f32x4*)(hr + c * 32);
                f32x4 y = *(const f32x4*)(hr + c * 32 + 4);
                hfrag[c] = pack8(x, y);
            }
        } else {
            const unsigned tgt = (unsigned)t;
            const unsigned int* src = hbT + (t & 1) * 32768 + b * 512 + l4 * 8;
            for (;;) {
                u32x4 ra[16], rb[16];
                LDT(0,  "0",    "16")   LDT(1,  "128",  "144")
                LDT(2,  "256",  "272")  LDT(3,  "384",  "400")
                LDT(4,  "512",  "528")  LDT(5,  "640",  "656")
                LDT(6,  "768",  "784")  LDT(7,  "896",  "912")
                LDT(8,  "1024", "1040") LDT(9,  "1152", "1168")
                LDT(10, "1280", "1296") LDT(11, "1408", "1424")
                LDT(12, "1536", "1552") LDT(13, "1664", "1680")
                LDT(14, "1792", "1808") LDT(15, "1920", "1936")
                vm_drain();
                __builtin_amdgcn_sched_barrier(0);
                // 16B granules are single VMEM transactions -> word0 tag suffices
                unsigned bad = 0;
#pragma unroll
                for (int c = 0; c < 16; c++) {
                    bad |= (ra[c][0] ^ tgt) & 0xFFFFu;
                    bad |= (rb[c][0] ^ tgt) & 0xFFFFu;
                }
                if (!__any((int)bad)) {
#pragma unroll
                    for (int c = 0; c < 16; c++) {
                        s16x8 f;
                        f[0] = (short)(ra[c][0] >> 16); f[1] = (short)(ra[c][1] >> 16);
                        f[2] = (short)(ra[c][2] >> 16); f[3] = (short)(ra[c][3] >> 16);
                        f[4] = (short)(rb[c][0] >> 16); f[5] = (short)(rb[c][1] >> 16);
                        f[6] = (short)(rb[c][2] >> 16); f[7] = (short)(rb[c][3] >> 16);
                        hfrag[c] = f;
                    }
                    break;
                }
                __builtin_amdgcn_s_sleep(1);
            }
        }

        f32x4 acc0 = {0.f, 0.f, 0.f, 0.f};
        f32x4 acc1 = {0.f, 0.f, 0.f, 0.f};
        f32x4 acc2 = {0.f, 0.f, 0.f, 0.f};
#pragma unroll
        for (int c = 0; c < 16; c++) {
            acc0 = mfma16(wf[0][c], hfrag[c], acc0);
            acc1 = mfma16(wf[1][c], hfrag[c], acc1);
            acc2 = mfma16(wf[2][c], hfrag[c], acc2);
        }

#pragma unroll
        for (int i = 0; i < 4; i++) {
            float rr = sigmoid_fast(bf2f((unsigned short)g0[i]) + acc0[i] + bh_r[i]);
            float zz = sigmoid_fast(bf2f((unsigned short)g1[i]) + acc1[i] + bh_z[i]);
            float nn = tanh_fast(bf2f((unsigned short)g2[i]) + rr * (acc2[i] + bh_n[i]));
            hp[i] = fmaf(zz, hp[i] - nn, nn);
        }

        float* hso = hs + ((size_t)t * 64 + b) * 512 + jb + jrow;
        f32x4 hv = {hp[0], hp[1], hp[2], hp[3]};

        if (t < 511) {
            // publish tagged h_{t+1}: fire-and-forget sc1 dwordx4 (tag inside data)
            if (writer) {
                const unsigned tag2 = (unsigned)(t + 1);
                u32x4 pv;
                pv[0] = ((unsigned)f2bf(hp[0]) << 16) | tag2;
                pv[1] = ((unsigned)f2bf(hp[1]) << 16) | tag2;
                pv[2] = ((unsigned)f2bf(hp[2]) << 16) | tag2;
                pv[3] = ((unsigned)f2bf(hp[3]) << 16) | tag2;
                unsigned int* dst = hbT + ((t + 1) & 1) * 32768 + b * 512 + jb + jrow;
                asm volatile("global_store_dwordx4 %0, %1, off sc1"
                             :: "v"(dst), "v"(pv) : "memory");
            }
            // Gi[t+1] prefetch + hs store fly under next poll
            s16x4 n0, n1, n2;
            {
                const unsigned short* gp = Gi + ((size_t)(t + 1) * 64 + b) * 1536 + jb + jrow;
                n0 = *(const s16x4*)(gp);
                n1 = *(const s16x4*)(gp + 512);
                n2 = *(const s16x4*)(gp + 1024);
            }
            if (writer) *(f32x4*)hso = hv;
            g0 = n0; g1 = n1; g2 = n2;
        } else {
            if (writer) *(f32x4*)hso = hv;
        }
    }
#undef LDT
}

// ---------------------------------------------------------------------------
// ws layout (bytes):
//   Pt  : [0, 64Mi)        f32   Qt: [64Mi,128Mi)   c: [128Mi,160Mi) bf16
//   Gi  : [0, 96Mi)        bf16 (overlays Pt/Qt, dead by then)
//   hbT : [160Mi, +256Ki)  u32 tagged h, zeroed per launch
// ---------------------------------------------------------------------------
extern "C" void kernel_launch(void* const* d_in, const int* in_sizes, int n_in,
                              void* d_out, int out_size, void* d_ws, size_t ws_size,
                              hipStream_t stream)
{
    (void)in_sizes; (void)n_in; (void)out_size; (void)ws_size;
    const float* v   = (const float*)d_in[0];
    const float* h0  = (const float*)d_in[1];
    const float* Vv  = (const float*)d_in[2];
    const float* Wp  = (const float*)d_in[3];
    const float* Wp_ = (const float*)d_in[4];
    const float* Wih = (const float*)d_in[5];
    const float* Whh = (const float*)d_in[6];
    const float* bih = (const float*)d_in[7];
    const float* bhh = (const float*)d_in[8];
    float* hs = (float*)d_out;

    char* ws = (char*)d_ws;
    float* Pt = (float*)(ws);
    float* Qt = (float*)(ws + 67108864ULL);
    unsigned short* cb  = (unsigned short*)(ws + 134217728ULL);
    unsigned short* Gi  = (unsigned short*)(ws);
    unsigned int*   hbT = (unsigned int*)(ws + 167772160ULL);

    hipMemsetAsync(hbT, 0, 2ULL * 32768ULL * 4ULL, stream);

    dim3 gpq(256, 4, 1);
    gemm_k<1, 1, 0, 0, 0><<<gpq, 256, 0, stream>>>(v, Wp, nullptr, Pt, 32768, 512);
    gemm_k<1, 1, 0, 0, 0><<<gpq, 256, 0, stream>>>(v, Wp_, nullptr, Qt, 32768, 512);

    att_k<<<dim3(32, 64), 512, 0, stream>>>(Pt, Qt, Vv, v, cb);

    gemm_k<0, 0, 1, 1, 1><<<dim3(256, 12), 256, 0, stream>>>(cb, Wih, bih, Gi, 32768, 1536);

    rec_k<<<dim3(64), 256, 0, stream>>>(Gi, Whh, bhh, h0, hbT, hs);
}